// Round 1
// baseline (22405.299 us; speedup 1.0000x reference)
//
#include <hip/hip_runtime.h>

// SentimentNet on MI355X — round 1: fp32-exact, persistent cooperative LSTM.
//
// Structure:
//  K1 (persistent, cooperative, 256 WGs x 512 thr):
//      8 teams (8 batches each) x 32 WGs (16 units each).
//      W_ih/W_hh rows register-stationary (64+64 VGPR/lane), k split over 8 waves.
//      Per step: stage embed (prefetched) + h (agent-scope loads) to LDS,
//      dual dot (xp + recurrent), LDS k-reduce, gates in fp32, h exchange via
//      LLC (agent-scope stores), per-team sense-reversing barrier.
//  K2: attention GEMM states@W_word with fused tanh*w_proj row-reduce -> 4 partials.
//  K3: per-batch softmax over S, pooled sum, decode to [1,64,2].

#define S_LEN 500
#define BATCH 64
#define EDIM 512
#define HDIM 512
#define TEAMS 8
#define WGS_PER_TEAM 32
#define TB 8                      // batches per team
#define NBLOCKS (TEAMS * WGS_PER_TEAM)
#define NTHREADS 512

// workspace layout (bytes)
#define STATES_BYTES (S_LEN * BATCH * HDIM * 4)        // 65,536,000
#define HBUF_OFF     STATES_BYTES
#define HBUF_BYTES   (2 * TEAMS * HDIM * TB * 4)       // 262,144
#define PART_OFF     (HBUF_OFF + HBUF_BYTES)           // 65,798,144
#define PART_BYTES   (4 * S_LEN * BATCH * 4)           // 512,000
#define BAR_OFF      (PART_OFF + PART_BYTES)           // 66,310,144
#define BAR_BYTES    4096

__device__ __forceinline__ void team_barrier(int* bar, int team, int target) {
  __syncthreads();                 // all waves' stores drained (vmcnt) before arrive
  if (threadIdx.x == 0) {
    __threadfence();
    int* cnt = bar + team * 32;    // 128B apart per team
    int* ep  = cnt + 1;
    int prev = __hip_atomic_fetch_add(cnt, 1, __ATOMIC_ACQ_REL, __HIP_MEMORY_SCOPE_AGENT);
    if (prev == WGS_PER_TEAM - 1) {
      __hip_atomic_store(cnt, 0, __ATOMIC_RELAXED, __HIP_MEMORY_SCOPE_AGENT);
      __hip_atomic_fetch_add(ep, 1, __ATOMIC_RELEASE, __HIP_MEMORY_SCOPE_AGENT);
    } else {
      int spins = 0;
      while (__hip_atomic_load(ep, __ATOMIC_ACQUIRE, __HIP_MEMORY_SCOPE_AGENT) < target) {
        if (++spins > (1 << 25)) break;      // bounded spin: never hang
        __builtin_amdgcn_s_sleep(2);
      }
    }
    __threadfence();
  }
  __syncthreads();
}

__global__ __launch_bounds__(NTHREADS, 2) void lstm_persistent(
    const int* __restrict__ idx, const float* __restrict__ emb,
    const float* __restrict__ W_ih, const float* __restrict__ W_hh,
    const float* __restrict__ b_ih, const float* __restrict__ b_hh,
    float* __restrict__ states, float* __restrict__ h_buf, int* bar) {
  __shared__ float embL[8][TB][64];   // [wave][batch][k-chunk]
  __shared__ float hL[8][TB][64];
  __shared__ float red[8][TB][64];    // [wave][batch][row]
  __shared__ float zL[TB][64];        // [batch][row]

  const int team = blockIdx.x >> 5;          // 0..7
  const int wg   = blockIdx.x & 31;          // 0..31 -> units [16wg,16wg+16)
  const int tid  = threadIdx.x;
  const int w    = tid >> 6;                 // wave 0..7 -> k chunk [64w,64w+64)
  const int l    = tid & 63;                 // lane -> row within WG

  // gate-row for (wg, lane): row r -> g = 16*wg + (r&15) + 512*(r>>4)
  const int g = 16 * wg + (l & 15) + 512 * (l >> 4);

  // register-stationary weights: this lane's row, this wave's 64-k chunk
  float wih[64], whh[64];
  {
    const float4* pih = (const float4*)(W_ih + (size_t)g * EDIM + (size_t)w * 64);
    const float4* phh = (const float4*)(W_hh + (size_t)g * HDIM + (size_t)w * 64);
#pragma unroll
    for (int j = 0; j < 16; ++j) {
      float4 v = pih[j];
      wih[4 * j + 0] = v.x; wih[4 * j + 1] = v.y; wih[4 * j + 2] = v.z; wih[4 * j + 3] = v.w;
    }
#pragma unroll
    for (int j = 0; j < 16; ++j) {
      float4 v = phh[j];
      whh[4 * j + 0] = v.x; whh[4 * j + 1] = v.y; whh[4 * j + 2] = v.z; whh[4 * j + 3] = v.w;
    }
  }

  // reduce-thread identity: (rr=row, rb=batch)
  const int rr = tid & 63, rb = tid >> 6;
  const int gr = 16 * wg + (rr & 15) + 512 * (rr >> 4);
  const float bias = b_ih[gr] + b_hh[gr];

  // gate-thread identity (tid<128): unit gu, batch gb
  const int gu = tid & 15, gb = tid >> 4;
  float c_state = 0.f;

  // prefetch embedding for s=0: lane l reads element (64w+l) of each batch row
  float ereg[TB];
#pragma unroll
  for (int b = 0; b < TB; ++b) {
    int row = idx[0 * BATCH + team * TB + b];
    ereg[b] = emb[(size_t)row * EDIM + (size_t)w * 64 + l];
  }

  for (int s = 0; s < S_LEN; ++s) {
    const int par = s & 1;
    // stage current embed chunk (own-wave region only: no __syncthreads needed)
#pragma unroll
    for (int b = 0; b < TB; ++b) embL[w][b][l] = ereg[b];

    // stage h(s-1): written by teammates at end of step s-1 with parity s&1
    float hl[TB];
    if (s > 0) {
#pragma unroll
      for (int b = 0; b < TB; ++b)
        hl[b] = __hip_atomic_load(
            &h_buf[((size_t)par * TEAMS + team) * HDIM * TB + (size_t)(w * 64 + l) * TB + b],
            __ATOMIC_RELAXED, __HIP_MEMORY_SCOPE_AGENT);
    }
    // issue embed prefetch for s+1 early (consumed next iteration)
    if (s + 1 < S_LEN) {
#pragma unroll
      for (int b = 0; b < TB; ++b) {
        int row = idx[(s + 1) * BATCH + team * TB + b];
        ereg[b] = emb[(size_t)row * EDIM + (size_t)w * 64 + l];
      }
    }
    if (s > 0) {
#pragma unroll
      for (int b = 0; b < TB; ++b) hL[w][b][l] = hl[b];
    }

    // dual dot: z_partial[b] = sum_k wih[k]*embed + sum_k whh[k]*h  (this wave's k chunk)
    float acc[TB];
#pragma unroll
    for (int b = 0; b < TB; ++b) {
      float a = 0.f;
      const float4* eb = (const float4*)&embL[w][b][0];
#pragma unroll
      for (int k4 = 0; k4 < 16; ++k4) {
        float4 e = eb[k4];
        a = fmaf(wih[4 * k4 + 0], e.x, a);
        a = fmaf(wih[4 * k4 + 1], e.y, a);
        a = fmaf(wih[4 * k4 + 2], e.z, a);
        a = fmaf(wih[4 * k4 + 3], e.w, a);
      }
      acc[b] = a;
    }
    if (s > 0) {
#pragma unroll
      for (int b = 0; b < TB; ++b) {
        float a = acc[b];
        const float4* hb = (const float4*)&hL[w][b][0];
#pragma unroll
        for (int k4 = 0; k4 < 16; ++k4) {
          float4 h4 = hb[k4];
          a = fmaf(whh[4 * k4 + 0], h4.x, a);
          a = fmaf(whh[4 * k4 + 1], h4.y, a);
          a = fmaf(whh[4 * k4 + 2], h4.z, a);
          a = fmaf(whh[4 * k4 + 3], h4.w, a);
        }
        acc[b] = a;
      }
    }
    // k-reduce across the 8 waves
#pragma unroll
    for (int b = 0; b < TB; ++b) red[w][b][l] = acc[b];
    __syncthreads();
    {
      float z = bias;
#pragma unroll
      for (int w2 = 0; w2 < 8; ++w2) z += red[w2][rb][rr];
      zL[rb][rr] = z;
    }
    __syncthreads();

    // gates: thread t<128 owns (unit gu, batch gb)
    if (tid < 128) {
      float zi = zL[gb][gu +  0];
      float zf = zL[gb][gu + 16];
      float zg = zL[gb][gu + 32];
      float zo = zL[gb][gu + 48];
      float i_ = 1.f / (1.f + expf(-zi));
      float f_ = 1.f / (1.f + expf(-zf));
      float o_ = 1.f / (1.f + expf(-zo));
      float g_ = tanhf(zg);
      c_state = f_ * c_state + i_ * g_;
      float h_ = o_ * tanhf(c_state);
      int unit = 16 * wg + gu;
      __hip_atomic_store(
          &h_buf[((size_t)((s + 1) & 1) * TEAMS + team) * HDIM * TB + (size_t)unit * TB + gb],
          h_, __ATOMIC_RELAXED, __HIP_MEMORY_SCOPE_AGENT);
      states[((size_t)s * BATCH + team * TB + gb) * HDIM + unit] = h_;
    }

    if (s + 1 < S_LEN) team_barrier(bar, team, s + 1);
  }
}

// ---------------- attention GEMM: tanh(states@W_word + b_word) @ w_proj ----------------
#define ATP 132
__global__ __launch_bounds__(256) void attn_gemm(
    const float* __restrict__ states, const float* __restrict__ W_word,
    const float* __restrict__ b_word, const float* __restrict__ w_proj,
    float* __restrict__ part) {
  __shared__ float At[16][ATP];   // A transposed tile [k][m]
  __shared__ float Bt[16][ATP];   // B tile [k][n]
  __shared__ float redl[128][17];

  const int tid = threadIdx.x;
  const int m0 = blockIdx.x * 128;   // token tile
  const int n0 = blockIdx.y * 128;   // tanh-dim tile
  const int ty = tid >> 4, tx = tid & 15;

  float acc[8][8];
#pragma unroll
  for (int i = 0; i < 8; ++i)
#pragma unroll
    for (int j = 0; j < 8; ++j) acc[i][j] = 0.f;

  for (int k0 = 0; k0 < 512; k0 += 16) {
#pragma unroll
    for (int it = 0; it < 2; ++it) {
      int m = (tid >> 2) + 64 * it;
      int kq = tid & 3;
      float4 v = *(const float4*)&states[(size_t)(m0 + m) * 512 + k0 + 4 * kq];
      At[4 * kq + 0][m] = v.x; At[4 * kq + 1][m] = v.y;
      At[4 * kq + 2][m] = v.z; At[4 * kq + 3][m] = v.w;
    }
#pragma unroll
    for (int it = 0; it < 2; ++it) {
      int kr = (tid >> 5) + 8 * it;
      int nq = tid & 31;
      float4 v = *(const float4*)&W_word[(size_t)(k0 + kr) * 512 + n0 + 4 * nq];
      *(float4*)&Bt[kr][4 * nq] = v;
    }
    __syncthreads();
#pragma unroll
    for (int kk = 0; kk < 16; ++kk) {
      float4 a0 = *(const float4*)&At[kk][ty * 8];
      float4 a1 = *(const float4*)&At[kk][ty * 8 + 4];
      float4 b0 = *(const float4*)&Bt[kk][tx * 8];
      float4 b1 = *(const float4*)&Bt[kk][tx * 8 + 4];
      float av[8] = {a0.x, a0.y, a0.z, a0.w, a1.x, a1.y, a1.z, a1.w};
      float bv[8] = {b0.x, b0.y, b0.z, b0.w, b1.x, b1.y, b1.z, b1.w};
#pragma unroll
      for (int i = 0; i < 8; ++i)
#pragma unroll
        for (int j = 0; j < 8; ++j) acc[i][j] = fmaf(av[i], bv[j], acc[i][j]);
    }
    __syncthreads();
  }
  // epilogue: tanh(acc + b_word[n]) * w_proj[n], reduce over this block's 128 n-cols
  float bw[8], wp[8];
  {
    float4 v0 = *(const float4*)&b_word[n0 + tx * 8];
    float4 v1 = *(const float4*)&b_word[n0 + tx * 8 + 4];
    bw[0]=v0.x; bw[1]=v0.y; bw[2]=v0.z; bw[3]=v0.w; bw[4]=v1.x; bw[5]=v1.y; bw[6]=v1.z; bw[7]=v1.w;
    float4 u0 = *(const float4*)&w_proj[n0 + tx * 8];
    float4 u1 = *(const float4*)&w_proj[n0 + tx * 8 + 4];
    wp[0]=u0.x; wp[1]=u0.y; wp[2]=u0.z; wp[3]=u0.w; wp[4]=u1.x; wp[5]=u1.y; wp[6]=u1.z; wp[7]=u1.w;
  }
#pragma unroll
  for (int i = 0; i < 8; ++i) {
    float rs = 0.f;
#pragma unroll
    for (int j = 0; j < 8; ++j) rs += tanhf(acc[i][j] + bw[j]) * wp[j];
    redl[ty * 8 + i][tx] = rs;
  }
  __syncthreads();
  if (tid < 128) {
    float ssum = 0.f;
#pragma unroll
    for (int x = 0; x < 16; ++x) ssum += redl[tid][x];
    part[(size_t)blockIdx.y * (S_LEN * BATCH) + m0 + tid] = ssum;
  }
}

// ---------------- softmax over S + pooled sum + decode ----------------
__global__ __launch_bounds__(256) void softmax_pool_decode(
    const float* __restrict__ part, const float* __restrict__ states,
    const float* __restrict__ dec_W, const float* __restrict__ dec_b,
    float* __restrict__ out) {
  const int b = blockIdx.x;
  const int tid = threadIdx.x;
  __shared__ float sc[S_LEN];
  __shared__ float pool[HDIM];
  __shared__ float redm[256];

  for (int s = tid; s < S_LEN; s += 256) {
    int t = s * BATCH + b;
    sc[s] = part[t] + part[S_LEN * BATCH + t] + part[2 * S_LEN * BATCH + t] +
            part[3 * S_LEN * BATCH + t];
  }
  __syncthreads();
  float m = -1e30f;
  for (int s = tid; s < S_LEN; s += 256) m = fmaxf(m, sc[s]);
  redm[tid] = m; __syncthreads();
  for (int o = 128; o > 0; o >>= 1) {
    if (tid < o) redm[tid] = fmaxf(redm[tid], redm[tid + o]);
    __syncthreads();
  }
  const float gmax = redm[0];
  __syncthreads();
  float lsum = 0.f;
  for (int s = tid; s < S_LEN; s += 256) { float e = expf(sc[s] - gmax); sc[s] = e; lsum += e; }
  redm[tid] = lsum; __syncthreads();
  for (int o = 128; o > 0; o >>= 1) {
    if (tid < o) redm[tid] += redm[tid + o];
    __syncthreads();
  }
  const float inv = 1.f / redm[0];
  __syncthreads();
  for (int h = tid; h < HDIM; h += 256) {
    float a = 0.f;
    for (int s = 0; s < S_LEN; ++s)
      a = fmaf(sc[s], states[((size_t)s * BATCH + b) * HDIM + h], a);
    pool[h] = a * inv;
  }
  __syncthreads();
  // decode: 2 halves of 128 threads, each sums 4 h-elems then tree-reduce
  const int lcls = tid >> 7, ch = tid & 127;
  float p = 0.f;
#pragma unroll
  for (int j = 0; j < 4; ++j)
    p = fmaf(pool[ch * 4 + j], dec_W[lcls * HDIM + ch * 4 + j], p);
  redm[tid] = p; __syncthreads();
  for (int o = 64; o > 0; o >>= 1) {
    if (ch < o) redm[tid] += redm[tid + o];
    __syncthreads();
  }
  if (ch == 0) out[b * 2 + lcls] = redm[tid] + dec_b[lcls];
}

extern "C" void kernel_launch(void* const* d_in, const int* in_sizes, int n_in,
                              void* d_out, int out_size, void* d_ws, size_t ws_size,
                              hipStream_t stream) {
  const int*   idx    = (const int*)d_in[0];
  // d_in[1] = text_lengths: unused by the reference
  const float* emb    = (const float*)d_in[2];
  const float* W_ih   = (const float*)d_in[3];
  const float* W_hh   = (const float*)d_in[4];
  const float* b_ih   = (const float*)d_in[5];
  const float* b_hh   = (const float*)d_in[6];
  const float* W_word = (const float*)d_in[7];
  const float* b_word = (const float*)d_in[8];
  const float* w_proj = (const float*)d_in[9];
  const float* dec_W  = (const float*)d_in[10];
  const float* dec_b  = (const float*)d_in[11];
  float* out = (float*)d_out;

  char* ws = (char*)d_ws;
  float* states = (float*)ws;
  float* h_buf  = (float*)(ws + HBUF_OFF);
  float* part   = (float*)(ws + PART_OFF);
  int*   bar    = (int*)(ws + BAR_OFF);

  // barrier state must start at 0 every launch (ws is not re-poisoned between replays)
  hipMemsetAsync(bar, 0, BAR_BYTES, stream);

  void* args[] = {(void*)&idx, (void*)&emb, (void*)&W_ih, (void*)&W_hh,
                  (void*)&b_ih, (void*)&b_hh, (void*)&states, (void*)&h_buf,
                  (void*)&bar};
  hipLaunchCooperativeKernel(lstm_persistent, dim3(NBLOCKS), dim3(NTHREADS), args, 0, stream);

  attn_gemm<<<dim3(250, 4), 256, 0, stream>>>(states, W_word, b_word, w_proj, part);
  softmax_pool_decode<<<64, 256, 0, stream>>>(part, states, dec_W, dec_b, out);
}